// Round 8
// baseline (149.505 us; speedup 1.0000x reference)
//
#include <hip/hip_runtime.h>
#include <hip/hip_bf16.h>

// PNAConvTower: h' = BN( snorm * ([x, PNA_aggr(x)] @ Wu + bu) )
// msg[e] = A[src[e]] + B[dst[e]] + bm   where A = x@Wm[:64], B = x@Wm[64:]
// Stats are shift-invariant: reduce over A[src] only, add (B[dst]+bm) at the end.
// CSR via 2-level counting sort (bucket = dst>>7); edge packed (src<<16)|dst
// (requires n <= 65535; here n = 50000).
// z = x@W0 + h@W1 + s1*(h@W2) + s2*(h@W3) + bu  (scalers folded, bf16 MFMA)
// BN column stats fused into the GEMM epilogue. 7 dispatches total.
// node_reduce: 8 edges per dwordx4 gather (8 lanes x 16B per A-row), named
// scalar accumulators only (promote-alloca puts arrays in LDS — R6 lesson).

#define DELTA_C 2.83f
#define BN_EPS_C 1e-5f
#define MOM_EPS_C 1e-30f
#define FLT_BIG 3.402823466e38f
#define BSHIFT 7            // 128 nodes per bucket
#define NBMAX 512           // supports n <= 65535

typedef __attribute__((ext_vector_type(8))) short bf16x8;   // 8 bf16 (4 VGPRs)
typedef __attribute__((ext_vector_type(4))) float f32x4;    // MFMA C/D frag

static __device__ __forceinline__ unsigned short f2bf(float f) {
    unsigned u = __float_as_uint(f);
    unsigned r = (u + 0x7FFFu + ((u >> 16) & 1u)) >> 16;    // RNE
    return (unsigned short)r;
}
static __device__ __forceinline__ unsigned pack2(float a, float b) {
    return (unsigned)f2bf(a) | ((unsigned)f2bf(b) << 16);
}
static __device__ __forceinline__ float bflo(unsigned u) { return __uint_as_float(u << 16); }
static __device__ __forceinline__ float bfhi(unsigned u) { return __uint_as_float(u & 0xFFFF0000u); }

// ---------------- K0: repack Wu into bf16 fragment order + zero accums ------
__global__ __launch_bounds__(256) void repack_wu(
    const float* __restrict__ Wu, short* __restrict__ Wup,
    int* __restrict__ bcnt, int* __restrict__ gcur, float* __restrict__ bnacc)
{
    int t = threadIdx.x;
    if (blockIdx.x == 0) {          // fold in the tiny zero-fills
        bcnt[t] = 0; bcnt[t + 256] = 0;
        gcur[t] = 0; gcur[t + 256] = 0;
        if (t < 128) bnacc[t] = 0.f;
    }
    int idx = blockIdx.x * 256 + t;                 // 26*256 == 26*4*64
    int lane = idx & 63, c = (idx >> 6) & 3, kc = idx >> 8;
    int kbase = kc * 32 + (lane >> 4) * 8;
    int col = c * 16 + (lane & 15);
    unsigned short o[8];
    #pragma unroll
    for (int i = 0; i < 8; ++i)
        o[i] = f2bf(Wu[(size_t)(kbase + i) * 64 + col]);
    uint4 u;
    u.x = o[0] | ((unsigned)o[1] << 16);
    u.y = o[2] | ((unsigned)o[3] << 16);
    u.z = o[4] | ((unsigned)o[5] << 16);
    u.w = o[6] | ((unsigned)o[7] << 16);
    *(uint4*)(Wup + (size_t)idx * 8) = u;
}

// ---------------- K1: A(bf16)=x@Wm_top, B(f32)=x@Wm_bot, xb=bf16(x) ---------
// + fused bucket histogram (first nb_chunk blocks each count a 4096-edge chunk)
__global__ __launch_bounds__(256) void proj_ab(
    const float* __restrict__ x, const float* __restrict__ Wm,
    unsigned* __restrict__ Ab, float* __restrict__ B,
    unsigned* __restrict__ xbu, int n,
    const int* __restrict__ dst, int* __restrict__ bcnt, int e, int nb_chunk)
{
    __shared__ float wm[128][68];
    __shared__ float xs[64][68];
    __shared__ int h[NBMAX];
    int t = threadIdx.x;
    for (int i = t; i < 2048; i += 256) {
        int k = i >> 4, c4 = (i & 15) << 2;
        *(float4*)&wm[k][c4] = *(const float4*)&Wm[k * 64 + c4];
    }
    int row0 = blockIdx.x * 64;
    for (int i = t; i < 1024; i += 256) {
        int r = i >> 4, k4 = (i & 15) << 2;
        int row = row0 + r;
        float4 v = make_float4(0.f, 0.f, 0.f, 0.f);
        if (row < n) v = *(const float4*)&x[(size_t)row * 64 + k4];
        *(float4*)&xs[r][k4] = v;
    }
    __syncthreads();
    int tr = t >> 4, tc = t & 15, c0 = tc << 2;
    float a[4][4] = {}; float b[4][4] = {};
    #pragma unroll 8
    for (int k = 0; k < 64; ++k) {
        float4 wa = *(float4*)&wm[k][c0];
        float4 wb = *(float4*)&wm[64 + k][c0];
        #pragma unroll
        for (int i = 0; i < 4; ++i) {
            float xv = xs[tr * 4 + i][k];
            a[i][0] += xv * wa.x; a[i][1] += xv * wa.y; a[i][2] += xv * wa.z; a[i][3] += xv * wa.w;
            b[i][0] += xv * wb.x; b[i][1] += xv * wb.y; b[i][2] += xv * wb.z; b[i][3] += xv * wb.w;
        }
    }
    #pragma unroll
    for (int i = 0; i < 4; ++i) {
        int r = tr * 4 + i;
        int row = row0 + r;
        uint2 xp;
        xp.x = pack2(xs[r][c0], xs[r][c0 + 1]);
        xp.y = pack2(xs[r][c0 + 2], xs[r][c0 + 3]);
        *(uint2*)&xbu[(size_t)row * 32 + (c0 >> 1)] = xp;
        if (row < n) {
            uint2 ap;
            ap.x = pack2(a[i][0], a[i][1]);
            ap.y = pack2(a[i][2], a[i][3]);
            *(uint2*)&Ab[(size_t)row * 32 + (c0 >> 1)] = ap;
            *(float4*)&B[(size_t)row * 64 + c0] = make_float4(b[i][0], b[i][1], b[i][2], b[i][3]);
        }
    }
    // fused bucket histogram (block-uniform guard -> barriers legal)
    if (blockIdx.x < nb_chunk) {
        __syncthreads();
        for (int bb = t; bb < NBMAX; bb += 256) h[bb] = 0;
        __syncthreads();
        int base = blockIdx.x * 4096;
        int cnt = min(4096, e - base);
        for (int i = t; i < cnt; i += 256)
            atomicAdd(&h[dst[base + i] >> BSHIFT], 1);
        __syncthreads();
        for (int bb = t; bb < NBMAX; bb += 256)
            if (h[bb]) atomicAdd(&bcnt[bb], h[bb]);
    }
}

// ---------------- K2c: bucket-major edge reorder (packed (src<<16)|dst) -----
// global bucket offsets recomputed in-block (bin_scan dispatch eliminated);
// gcur is a zero-based relative cursor.
__global__ __launch_bounds__(256) void bin_scatter(
    const int* __restrict__ src, const int* __restrict__ dst,
    const int* __restrict__ bcnt, int* __restrict__ gcur,
    unsigned* __restrict__ pairs_out, int e)
{
    __shared__ int hcnt[NBMAX], hstart[NBMAX], hcur[NBMAX], gpos[NBMAX], sgoff[NBMAX];
    __shared__ unsigned pairs[4096];
    int t = threadIdx.x;
    int base = blockIdx.x * 4096;
    int cnt = min(4096, e - base);
    for (int b = t; b < NBMAX; b += 256) hcnt[b] = 0;
    // in-block global bucket prefix (exclusive scan of bcnt)
    if (t < 64) {
        int v0 = bcnt[t * 8],     v1 = bcnt[t * 8 + 1], v2 = bcnt[t * 8 + 2], v3 = bcnt[t * 8 + 3];
        int v4 = bcnt[t * 8 + 4], v5 = bcnt[t * 8 + 5], v6 = bcnt[t * 8 + 6], v7 = bcnt[t * 8 + 7];
        int s = v0 + v1 + v2 + v3 + v4 + v5 + v6 + v7;
        int inc = s;
        #pragma unroll
        for (int st = 1; st < 64; st <<= 1) {
            int u = __shfl_up(inc, st);
            if (t >= st) inc += u;
        }
        int ex = inc - s;
        sgoff[t * 8] = ex;         ex += v0;
        sgoff[t * 8 + 1] = ex;     ex += v1;
        sgoff[t * 8 + 2] = ex;     ex += v2;
        sgoff[t * 8 + 3] = ex;     ex += v3;
        sgoff[t * 8 + 4] = ex;     ex += v4;
        sgoff[t * 8 + 5] = ex;     ex += v5;
        sgoff[t * 8 + 6] = ex;     ex += v6;
        sgoff[t * 8 + 7] = ex;
    }
    __syncthreads();

    int ls[16], ld[16];
    #pragma unroll
    for (int j = 0; j < 16; ++j) {
        int i = t + j * 256;
        ls[j] = 0; ld[j] = -1;
        if (i < cnt) {
            ls[j] = src[base + i];
            ld[j] = dst[base + i];
            atomicAdd(&hcnt[ld[j] >> BSHIFT], 1);
        }
    }
    __syncthreads();
    if (t < 64) {                             // exclusive prefix over 512 buckets
        int v[8]; int s = 0;
        #pragma unroll
        for (int j = 0; j < 8; ++j) { v[j] = hcnt[t * 8 + j]; s += v[j]; }
        int inc = s;
        #pragma unroll
        for (int st = 1; st < 64; st <<= 1) {
            int u = __shfl_up(inc, st);
            if (t >= st) inc += u;
        }
        int ex = inc - s;
        #pragma unroll
        for (int j = 0; j < 8; ++j) {
            hstart[t * 8 + j] = ex;
            hcur[t * 8 + j] = ex;
            ex += v[j];
        }
    }
    __syncthreads();
    #pragma unroll
    for (int j = 0; j < 16; ++j) {
        if (ld[j] >= 0) {
            int pos = atomicAdd(&hcur[ld[j] >> BSHIFT], 1);
            pairs[pos] = ((unsigned)ls[j] << 16) | (unsigned)ld[j];
        }
    }
    __syncthreads();
    for (int b = t; b < NBMAX; b += 256) {    // one global atomic per (block,bucket)
        int c = hcnt[b];
        if (c) gpos[b] = sgoff[b] + atomicAdd(&gcur[b], c);
    }
    __syncthreads();
    #pragma unroll
    for (int j = 0; j < 16; ++j) {
        int i = t + j * 256;
        if (i < cnt) {
            unsigned p = pairs[i];
            int b = (int)(p & 0xFFFFu) >> BSHIFT;   // bucket from packed dst
            pairs_out[gpos[b] + (i - hstart[b])] = p;
        }
    }
}

// ---------------- K2d: per-bucket CSR fill + offs ---------------------------
__global__ __launch_bounds__(128) void csr_fill(
    const unsigned* __restrict__ pairs, const int* __restrict__ bcnt,
    int* __restrict__ offs, int* __restrict__ csr, int n, int e)
{
    __shared__ int hist[128], pref[128], cur[128], sbase[1];
    int b = blockIdx.x, t = threadIdx.x;
    // in-block prefix of bcnt[0..b)
    if (t < 64) {
        int acc = 0;
        for (int k = t; k < b; k += 64) acc += bcnt[k];
        acc += __shfl_down(acc, 32); acc += __shfl_down(acc, 16);
        acc += __shfl_down(acc, 8);  acc += __shfl_down(acc, 4);
        acc += __shfl_down(acc, 2);  acc += __shfl_down(acc, 1);
        if (t == 0) sbase[0] = acc;
    }
    hist[t] = 0;
    __syncthreads();
    int base = sbase[0], cnt = bcnt[b];
    int node0 = b << BSHIFT;
    for (int i = t; i < cnt; i += 128)
        atomicAdd(&hist[pairs[base + i] & 127u], 1);
    __syncthreads();
    if (t < 64) {
        int v0 = hist[2 * t], v1 = hist[2 * t + 1];
        int s = v0 + v1, inc = s;
        #pragma unroll
        for (int st = 1; st < 64; st <<= 1) {
            int u = __shfl_up(inc, st);
            if (t >= st) inc += u;
        }
        int ex = inc - s;
        pref[2 * t] = ex;       cur[2 * t] = ex;
        pref[2 * t + 1] = ex + v0; cur[2 * t + 1] = ex + v0;
    }
    __syncthreads();
    int node = node0 + t;
    if (node < n) offs[node] = base + pref[t];
    if (b == gridDim.x - 1 && t == 0) offs[n] = e;
    for (int i = t; i < cnt; i += 128) {
        unsigned p = pairs[base + i];
        int pos = atomicAdd(&cur[p & 127u], 1);
        csr[base + pos] = (int)(p >> 16);
    }
}

// ---------------- K5: per-node multi-stat reduction (1 wave / node) ---------
// 8 edges per dwordx4 gather: lane = (edge group g=l>>3, column chunk q=l&7);
// each lane owns 8 bf16 columns; groups merged via shfl_xor(8/16/32).
__global__ __launch_bounds__(256) void node_reduce(
    const unsigned* __restrict__ Ab, const float* __restrict__ Bp,
    const float* __restrict__ bm,
    const int* __restrict__ offs, const int* __restrict__ csr,
    unsigned* __restrict__ hbu, float* __restrict__ s1, float* __restrict__ s2,
    int n, int npad)
{
    int wid = threadIdx.x >> 6;
    int lane = threadIdx.x & 63;
    int node = blockIdx.x * 4 + wid;
    if (node >= npad) return;
    unsigned* hrow = hbu + (size_t)node * 128;   // 256 bf16 = 128 uints
    int g = lane >> 3;          // edge slot 0..7
    int q = lane & 7;           // 16B column chunk 0..7
    int beg = 0, dg = 0;
    if (node < n) { beg = offs[node]; dg = offs[node + 1] - beg; }
    if (dg == 0) {
        if (lane < 8) {
            uint4 zz = make_uint4(0u, 0u, 0u, 0u);
            *(uint4*)&hrow[q * 4]      = zz;
            *(uint4*)&hrow[32 + q * 4] = zz;
            *(uint4*)&hrow[64 + q * 4] = zz;
            *(uint4*)&hrow[96 + q * 4] = zz;
        }
        if (lane == 0) { s1[node] = 0.f; s2[node] = 0.f; }
        return;
    }

    float as0 = 0.f, as1 = 0.f, as2 = 0.f, as3 = 0.f, as4 = 0.f, as5 = 0.f, as6 = 0.f, as7 = 0.f;
    float aq0 = 0.f, aq1 = 0.f, aq2 = 0.f, aq3 = 0.f, aq4 = 0.f, aq5 = 0.f, aq6 = 0.f, aq7 = 0.f;
    float ax0 = -FLT_BIG, ax1 = -FLT_BIG, ax2 = -FLT_BIG, ax3 = -FLT_BIG,
          ax4 = -FLT_BIG, ax5 = -FLT_BIG, ax6 = -FLT_BIG, ax7 = -FLT_BIG;
    float am0 = FLT_BIG, am1 = FLT_BIG, am2 = FLT_BIG, am3 = FLT_BIG,
          am4 = FLT_BIG, am5 = FLT_BIG, am6 = FLT_BIG, am7 = FLT_BIG;

#define ACCP(u, S0, Q0, X0, M0, S1_, Q1_, X1_, M1_) {                         \
    float v0 = bflo(u), v1 = bfhi(u);                                         \
    S0 += v0; Q0 = fmaf(v0, v0, Q0); X0 = fmaxf(X0, v0); M0 = fminf(M0, v0);  \
    S1_ += v1; Q1_ = fmaf(v1, v1, Q1_); X1_ = fmaxf(X1_, v1); M1_ = fminf(M1_, v1); }
#define ACC8(V) {                                          \
    ACCP((V).x, as0, aq0, ax0, am0, as1, aq1, ax1, am1);   \
    ACCP((V).y, as2, aq2, ax2, am2, as3, aq3, ax3, am3);   \
    ACCP((V).z, as4, aq4, ax4, am4, as5, aq5, ax5, am5);   \
    ACCP((V).w, as6, aq6, ax6, am6, as7, aq7, ax7, am7); }
#define GA4(idx) (((const uint4*)Ab)[(size_t)(idx) * 8 + q])

    int j = beg, end = beg + dg;
    for (; j + 15 < end; j += 16) {          // 16 edges, 2 dwordx4 gathers
        int ia = csr[j + g];
        int ib = csr[j + 8 + g];
        uint4 va = GA4(ia);
        uint4 vb = GA4(ib);
        ACC8(va); ACC8(vb);
    }
    for (; j + 7 < end; j += 8) {            // 8 edges, 1 gather
        int ia = csr[j + g];
        uint4 va = GA4(ia);
        ACC8(va);
    }
    if (j < end) {                           // tail < 8 edges (group-masked)
        int jp = j + g; if (jp > end - 1) jp = end - 1;
        int ia = csr[jp];
        uint4 va = GA4(ia);
        if (j + g < end) ACC8(va);
    }
#undef GA4
#undef ACC8
#undef ACCP

    // merge edge groups (lane bits 3,4,5)
#define RSUM(a) { a += __shfl_xor(a, 8); a += __shfl_xor(a, 16); a += __shfl_xor(a, 32); }
#define RMAX(a) { a = fmaxf(a, __shfl_xor(a, 8)); a = fmaxf(a, __shfl_xor(a, 16)); a = fmaxf(a, __shfl_xor(a, 32)); }
#define RMIN(a) { a = fminf(a, __shfl_xor(a, 8)); a = fminf(a, __shfl_xor(a, 16)); a = fminf(a, __shfl_xor(a, 32)); }
    RSUM(as0); RSUM(as1); RSUM(as2); RSUM(as3); RSUM(as4); RSUM(as5); RSUM(as6); RSUM(as7);
    RSUM(aq0); RSUM(aq1); RSUM(aq2); RSUM(aq3); RSUM(aq4); RSUM(aq5); RSUM(aq6); RSUM(aq7);
    RMAX(ax0); RMAX(ax1); RMAX(ax2); RMAX(ax3); RMAX(ax4); RMAX(ax5); RMAX(ax6); RMAX(ax7);
    RMIN(am0); RMIN(am1); RMIN(am2); RMIN(am3); RMIN(am4); RMIN(am5); RMIN(am6); RMIN(am7);
#undef RSUM
#undef RMAX
#undef RMIN

    if (lane < 8) {
        float fd = (float)dg, inv = 1.0f / fd;
        float4 bA = *(const float4*)(Bp + (size_t)node * 64 + q * 8);
        float4 bB = *(const float4*)(Bp + (size_t)node * 64 + q * 8 + 4);
        float4 mA = *(const float4*)(bm + q * 8);
        float4 mB = *(const float4*)(bm + q * 8 + 4);
        float bn0 = bA.x + mA.x, bn1 = bA.y + mA.y, bn2 = bA.z + mA.z, bn3 = bA.w + mA.w;
        float bn4 = bB.x + mB.x, bn5 = bB.y + mB.y, bn6 = bB.z + mB.z, bn7 = bB.w + mB.w;
#define FIN(S, Q, ME, SD) { ME = S * inv; float vv = Q * inv - ME * ME;       \
    if (vv < 0.f) vv = 0.f; SD = sqrtf(vv + MOM_EPS_C); }
        float me0, me1, me2, me3, me4, me5, me6, me7;
        float sd0, sd1, sd2, sd3, sd4, sd5, sd6, sd7;
        FIN(as0, aq0, me0, sd0); FIN(as1, aq1, me1, sd1);
        FIN(as2, aq2, me2, sd2); FIN(as3, aq3, me3, sd3);
        FIN(as4, aq4, me4, sd4); FIN(as5, aq5, me5, sd5);
        FIN(as6, aq6, me6, sd6); FIN(as7, aq7, me7, sd7);
#undef FIN
        uint4 wmean = make_uint4(pack2(me0 + bn0, me1 + bn1), pack2(me2 + bn2, me3 + bn3),
                                 pack2(me4 + bn4, me5 + bn5), pack2(me6 + bn6, me7 + bn7));
        uint4 wmax  = make_uint4(pack2(ax0 + bn0, ax1 + bn1), pack2(ax2 + bn2, ax3 + bn3),
                                 pack2(ax4 + bn4, ax5 + bn5), pack2(ax6 + bn6, ax7 + bn7));
        uint4 wmin  = make_uint4(pack2(am0 + bn0, am1 + bn1), pack2(am2 + bn2, am3 + bn3),
                                 pack2(am4 + bn4, am5 + bn5), pack2(am6 + bn6, am7 + bn7));
        uint4 wstd  = make_uint4(pack2(sd0, sd1), pack2(sd2, sd3),
                                 pack2(sd4, sd5), pack2(sd6, sd7));
        *(uint4*)&hrow[q * 4]      = wmean;
        *(uint4*)&hrow[32 + q * 4] = wmax;
        *(uint4*)&hrow[64 + q * 4] = wmin;
        *(uint4*)&hrow[96 + q * 4] = wstd;
    }
    if (lane == 0) {
        float fd = (float)dg;
        float logD = logf(fd + 1.0f);
        s1[node] = logD / DELTA_C;
        s2[node] = DELTA_C / logD;
    }
}

// ---------------- K6: MFMA update GEMM + fused BN column stats --------------
__global__ __launch_bounds__(256) void gemm_mfma(
    const short* __restrict__ xb, const short* __restrict__ hb,
    const float* __restrict__ s1p, const float* __restrict__ s2p,
    const short* __restrict__ Wup, const float* __restrict__ bu,
    float* __restrict__ z, float* __restrict__ bnacc, int n, float snorm)
{
    __shared__ float bnl[4][2][64];
    int t = threadIdx.x;
    int lane = t & 63, w = t >> 6;
    int rb = blockIdx.x * 128 + w * 32;
    int r16 = lane & 15, kg = lane >> 4;

    f32x4 accx[2][4] = {};
    f32x4 acc1[2][4] = {};
    f32x4 acc2[2][4] = {};
    f32x4 acc3[2][4] = {};

    const short* xr0 = xb + (size_t)(rb + r16) * 64 + kg * 8;
    const short* xr1 = xr0 + 16 * 64;

    #pragma unroll
    for (int kc = 0; kc < 2; ++kc) {
        bf16x8 a0 = *(const bf16x8*)(xr0 + kc * 32);
        bf16x8 a1 = *(const bf16x8*)(xr1 + kc * 32);
        #pragma unroll
        for (int c = 0; c < 4; ++c) {
            bf16x8 b = *(const bf16x8*)(Wup + (size_t)((kc * 4 + c) * 64 + lane) * 8);
            accx[0][c] = __builtin_amdgcn_mfma_f32_16x16x32_bf16(a0, b, accx[0][c], 0, 0, 0);
            accx[1][c] = __builtin_amdgcn_mfma_f32_16x16x32_bf16(a1, b, accx[1][c], 0, 0, 0);
        }
    }

    const short* hr0 = hb + (size_t)(rb + r16) * 256 + kg * 8;
    const short* hr1 = hr0 + 16 * 256;

    #pragma unroll 1
    for (int kh = 0; kh < 8; ++kh) {
        bf16x8 a0 = *(const bf16x8*)(hr0 + kh * 32);
        bf16x8 a1 = *(const bf16x8*)(hr1 + kh * 32);
        #pragma unroll
        for (int c = 0; c < 4; ++c) {
            bf16x8 b1 = *(const bf16x8*)(Wup + (size_t)(((2  + kh) * 4 + c) * 64 + lane) * 8);
            bf16x8 b2 = *(const bf16x8*)(Wup + (size_t)(((10 + kh) * 4 + c) * 64 + lane) * 8);
            bf16x8 b3 = *(const bf16x8*)(Wup + (size_t)(((18 + kh) * 4 + c) * 64 + lane) * 8);
            acc1[0][c] = __builtin_amdgcn_mfma_f32_16x16x32_bf16(a0, b1, acc1[0][c], 0, 0, 0);
            acc1[1][c] = __builtin_amdgcn_mfma_f32_16x16x32_bf16(a1, b1, acc1[1][c], 0, 0, 0);
            acc2[0][c] = __builtin_amdgcn_mfma_f32_16x16x32_bf16(a0, b2, acc2[0][c], 0, 0, 0);
            acc2[1][c] = __builtin_amdgcn_mfma_f32_16x16x32_bf16(a1, b2, acc2[1][c], 0, 0, 0);
            acc3[0][c] = __builtin_amdgcn_mfma_f32_16x16x32_bf16(a0, b3, acc3[0][c], 0, 0, 0);
            acc3[1][c] = __builtin_amdgcn_mfma_f32_16x16x32_bf16(a1, b3, acc3[1][c], 0, 0, 0);
        }
    }

    // epilogue: C/D frag layout col=lane&15, row=(lane>>4)*4+reg  [verified]
    float cs[4] = {}, css[4] = {};            // per-thread BN partials (4 cols)
    #pragma unroll
    for (int s = 0; s < 2; ++s) {
        int r0 = rb + s * 16 + kg * 4;
        float s1v[4], s2v[4];
        #pragma unroll
        for (int r = 0; r < 4; ++r) { s1v[r] = s1p[r0 + r]; s2v[r] = s2p[r0 + r]; }
        #pragma unroll
        for (int c = 0; c < 4; ++c) {
            int col = c * 16 + r16;
            float bval = bu[col];
            #pragma unroll
            for (int r = 0; r < 4; ++r) {
                int row = r0 + r;
                if (row < n) {
                    float v = (accx[s][c][r] + acc1[s][c][r]
                            + s1v[r] * acc2[s][c][r] + s2v[r] * acc3[s][c][r] + bval) * snorm;
                    z[(size_t)row * 64 + col] = v;
                    cs[c] += v;
                    css[c] = fmaf(v, v, css[c]);
                }
            }
        }
    }
    // butterfly over kg (lanes xor 16,32): all lanes end with the kg-sum
    #pragma unroll
    for (int c = 0; c < 4; ++c) {
        float a = cs[c];  a += __shfl_xor(a, 16); a += __shfl_xor(a, 32); cs[c] = a;
        float b = css[c]; b += __shfl_xor(b, 16); b += __shfl_xor(b, 32); css[c] = b;
    }
    if (lane < 16) {
        #pragma unroll
        for (int c = 0; c < 4; ++c) {
            bnl[w][0][c * 16 + lane] = cs[c];
            bnl[w][1][c * 16 + lane] = css[c];
        }
    }
    __syncthreads();
    if (t < 128) {
        int st = t >> 6, cc = t & 63;
        float tot = bnl[0][st][cc] + bnl[1][st][cc] + bnl[2][st][cc] + bnl[3][st][cc];
        atomicAdd(&bnacc[st * 64 + cc], tot);
    }
}

// ---------------- K8: BN normalize (in place on d_out, float4/thread) -------
__global__ __launch_bounds__(256) void bn_apply(
    float* __restrict__ z, const float* __restrict__ acc,
    const float* __restrict__ gamma, const float* __restrict__ beta, int n)
{
    float inv_n = 1.0f / (float)n;
    int tid = blockIdx.x * 256 + threadIdx.x;
    int c0 = (tid * 4) & 63;                    // fixed columns for this thread
    float sc[4], sh[4];
    #pragma unroll
    for (int k = 0; k < 4; ++k) {
        int c = c0 + k;
        float mu = acc[c] * inv_n;
        float var = acc[64 + c] * inv_n - mu * mu;
        if (var < 0.f) var = 0.f;
        float inv = rsqrtf(var + BN_EPS_C) * gamma[c];
        sc[k] = inv;
        sh[k] = beta[c] - mu * inv;
    }
    int total4 = n * 16;                        // n*64 / 4
    int stride = gridDim.x * 256;               // *4 floats: multiple of 64 ✓
    for (int i = tid; i < total4; i += stride) {
        float4 v = *(float4*)&z[(size_t)i * 4];
        v.x = fmaf(v.x, sc[0], sh[0]);
        v.y = fmaf(v.y, sc[1], sh[1]);
        v.z = fmaf(v.z, sc[2], sh[2]);
        v.w = fmaf(v.w, sc[3], sh[3]);
        *(float4*)&z[(size_t)i * 4] = v;
    }
}

extern "C" void kernel_launch(void* const* d_in, const int* in_sizes, int n_in,
                              void* d_out, int out_size, void* d_ws, size_t ws_size,
                              hipStream_t stream)
{
    const float* x     = (const float*)d_in[0];
    const float* Wm    = (const float*)d_in[1];
    const float* bm    = (const float*)d_in[2];
    const float* Wu    = (const float*)d_in[3];
    const float* bu    = (const float*)d_in[4];
    const float* gamma = (const float*)d_in[5];
    const float* beta  = (const float*)d_in[6];
    const int*   src   = (const int*)d_in[7];
    const int*   dst   = (const int*)d_in[8];

    int n = in_sizes[0] / 64;
    int e = in_sizes[7];
    int npad = ((n + 127) / 128) * 128;
    int nb = (n + 127) >> BSHIFT;          // buckets (<=512 for n<=65535)
    float* z = (float*)d_out;

    char* w = (char*)d_ws;
    size_t off = 0;
    auto take = [&](size_t bytes) -> void* {
        void* p = w + off;
        off = (off + bytes + 255) & ~(size_t)255;
        return p;
    };
    unsigned* Ab    = (unsigned*)take((size_t)npad * 32 * sizeof(unsigned));
    float*    B     = (float*)take((size_t)n * 64 * sizeof(float));
    unsigned* xbu   = (unsigned*)take((size_t)npad * 32 * sizeof(unsigned));
    unsigned* hbu   = (unsigned*)take((size_t)npad * 128 * sizeof(unsigned));
    float*    s1    = (float*)take((size_t)npad * sizeof(float));
    float*    s2    = (float*)take((size_t)npad * sizeof(float));
    short*    Wup   = (short*)take((size_t)26 * 4 * 64 * 8 * sizeof(short));
    int*      offs  = (int*)take((size_t)(n + 1) * sizeof(int));
    int*      csr   = (int*)take((size_t)e * sizeof(int));
    unsigned* prs   = (unsigned*)take((size_t)e * sizeof(unsigned));
    int*      bcnt  = (int*)take((size_t)NBMAX * sizeof(int));
    int*      gcur  = (int*)take((size_t)NBMAX * sizeof(int));
    float*    bnacc = (float*)take(128 * sizeof(float));

    (void)n_in; (void)out_size; (void)ws_size;

    int nb_rows64 = npad / 64;
    int nb_chunk = (e + 4095) / 4096;

    repack_wu<<<26, 256, 0, stream>>>(Wu, Wup, bcnt, gcur, bnacc);
    proj_ab<<<nb_rows64, 256, 0, stream>>>(x, Wm, Ab, B, xbu, n, dst, bcnt, e, nb_chunk);
    bin_scatter<<<nb_chunk, 256, 0, stream>>>(src, dst, bcnt, gcur, prs, e);
    csr_fill<<<nb, 128, 0, stream>>>(prs, bcnt, offs, csr, n, e);
    node_reduce<<<(npad + 3) / 4, 256, 0, stream>>>(Ab, B, bm, offs, csr, hbu, s1, s2, n, npad);

    float snorm = (float)(1.0 / sqrt((double)n));
    gemm_mfma<<<npad / 128, 256, 0, stream>>>((const short*)xbu, (const short*)hbu,
                                              s1, s2, Wup, bu, z, bnacc, n, snorm);

    bn_apply<<<512, 256, 0, stream>>>(z, bnacc, gamma, beta, n);
}

// Round 9
// 120.530 us; speedup vs baseline: 1.2404x; 1.2404x over previous
//
#include <hip/hip_runtime.h>
#include <hip/hip_bf16.h>

// PNAConvTower: h' = BN( snorm * ([x, PNA_aggr(x)] @ Wu + bu) )
// msg[e] = A[src[e]] + B[dst[e]] + bm   where A = x@Wm[:64], B = x@Wm[64:]
// Stats are shift-invariant: reduce over A[src] only, add (B[dst]+bm) at the end.
// CSR via 2-level counting sort (bucket = dst>>7); edge packed (src<<16)|dst
// (requires n <= 65535; here n = 50000).
// z = x@W0 + h@W1 + s1*(h@W2) + s2*(h@W3) + bu  (scalers folded, bf16 MFMA)
// BN column stats fused into the GEMM epilogue. 7 dispatches total.
// node_reduce lessons: (R6) no private arrays — promote-alloca puts them in
// LDS (16KB, 9M bank conflicts); (R8) keep the cross-lane merge NARROW — the
// 8-lane x 16B gather variant needed 96 ds_swizzle/node vs 8 here and went
// VALU-bound (84.7% busy, 69us). Half-wave + 8 shuffles is the sweet spot.

#define DELTA_C 2.83f
#define BN_EPS_C 1e-5f
#define MOM_EPS_C 1e-30f
#define FLT_BIG 3.402823466e38f
#define BSHIFT 7            // 128 nodes per bucket
#define NBMAX 512           // supports n <= 65535

typedef __attribute__((ext_vector_type(8))) short bf16x8;   // 8 bf16 (4 VGPRs)
typedef __attribute__((ext_vector_type(4))) float f32x4;    // MFMA C/D frag

static __device__ __forceinline__ unsigned short f2bf(float f) {
    unsigned u = __float_as_uint(f);
    unsigned r = (u + 0x7FFFu + ((u >> 16) & 1u)) >> 16;    // RNE
    return (unsigned short)r;
}
static __device__ __forceinline__ unsigned pack2(float a, float b) {
    return (unsigned)f2bf(a) | ((unsigned)f2bf(b) << 16);
}
static __device__ __forceinline__ float bflo(unsigned u) { return __uint_as_float(u << 16); }
static __device__ __forceinline__ float bfhi(unsigned u) { return __uint_as_float(u & 0xFFFF0000u); }

// ---------------- K0: repack Wu into bf16 fragment order + zero accums ------
__global__ __launch_bounds__(256) void repack_wu(
    const float* __restrict__ Wu, short* __restrict__ Wup,
    int* __restrict__ bcnt, int* __restrict__ gcur, float* __restrict__ bnacc)
{
    int t = threadIdx.x;
    if (blockIdx.x == 0) {          // fold in the tiny zero-fills
        bcnt[t] = 0; bcnt[t + 256] = 0;
        gcur[t] = 0; gcur[t + 256] = 0;
        if (t < 128) bnacc[t] = 0.f;
    }
    int idx = blockIdx.x * 256 + t;                 // 26*256 == 26*4*64
    int lane = idx & 63, c = (idx >> 6) & 3, kc = idx >> 8;
    int kbase = kc * 32 + (lane >> 4) * 8;
    int col = c * 16 + (lane & 15);
    unsigned short o[8];
    #pragma unroll
    for (int i = 0; i < 8; ++i)
        o[i] = f2bf(Wu[(size_t)(kbase + i) * 64 + col]);
    uint4 u;
    u.x = o[0] | ((unsigned)o[1] << 16);
    u.y = o[2] | ((unsigned)o[3] << 16);
    u.z = o[4] | ((unsigned)o[5] << 16);
    u.w = o[6] | ((unsigned)o[7] << 16);
    *(uint4*)(Wup + (size_t)idx * 8) = u;
}

// ---------------- K1: A(bf16)=x@Wm_top, B(f32)=x@Wm_bot, xb=bf16(x) ---------
// + fused bucket histogram (first nb_chunk blocks each count a 4096-edge chunk)
__global__ __launch_bounds__(256) void proj_ab(
    const float* __restrict__ x, const float* __restrict__ Wm,
    unsigned* __restrict__ Ab, float* __restrict__ B,
    unsigned* __restrict__ xbu, int n,
    const int* __restrict__ dst, int* __restrict__ bcnt, int e, int nb_chunk)
{
    __shared__ float wm[128][68];
    __shared__ float xs[64][68];
    __shared__ int h[NBMAX];
    int t = threadIdx.x;
    for (int i = t; i < 2048; i += 256) {
        int k = i >> 4, c4 = (i & 15) << 2;
        *(float4*)&wm[k][c4] = *(const float4*)&Wm[k * 64 + c4];
    }
    int row0 = blockIdx.x * 64;
    for (int i = t; i < 1024; i += 256) {
        int r = i >> 4, k4 = (i & 15) << 2;
        int row = row0 + r;
        float4 v = make_float4(0.f, 0.f, 0.f, 0.f);
        if (row < n) v = *(const float4*)&x[(size_t)row * 64 + k4];
        *(float4*)&xs[r][k4] = v;
    }
    __syncthreads();
    int tr = t >> 4, tc = t & 15, c0 = tc << 2;
    float a[4][4] = {}; float b[4][4] = {};
    #pragma unroll 8
    for (int k = 0; k < 64; ++k) {
        float4 wa = *(float4*)&wm[k][c0];
        float4 wb = *(float4*)&wm[64 + k][c0];
        #pragma unroll
        for (int i = 0; i < 4; ++i) {
            float xv = xs[tr * 4 + i][k];
            a[i][0] += xv * wa.x; a[i][1] += xv * wa.y; a[i][2] += xv * wa.z; a[i][3] += xv * wa.w;
            b[i][0] += xv * wb.x; b[i][1] += xv * wb.y; b[i][2] += xv * wb.z; b[i][3] += xv * wb.w;
        }
    }
    #pragma unroll
    for (int i = 0; i < 4; ++i) {
        int r = tr * 4 + i;
        int row = row0 + r;
        uint2 xp;
        xp.x = pack2(xs[r][c0], xs[r][c0 + 1]);
        xp.y = pack2(xs[r][c0 + 2], xs[r][c0 + 3]);
        *(uint2*)&xbu[(size_t)row * 32 + (c0 >> 1)] = xp;
        if (row < n) {
            uint2 ap;
            ap.x = pack2(a[i][0], a[i][1]);
            ap.y = pack2(a[i][2], a[i][3]);
            *(uint2*)&Ab[(size_t)row * 32 + (c0 >> 1)] = ap;
            *(float4*)&B[(size_t)row * 64 + c0] = make_float4(b[i][0], b[i][1], b[i][2], b[i][3]);
        }
    }
    // fused bucket histogram (block-uniform guard -> barriers legal)
    if (blockIdx.x < nb_chunk) {
        __syncthreads();
        for (int bb = t; bb < NBMAX; bb += 256) h[bb] = 0;
        __syncthreads();
        int base = blockIdx.x * 4096;
        int cnt = min(4096, e - base);
        for (int i = t; i < cnt; i += 256)
            atomicAdd(&h[dst[base + i] >> BSHIFT], 1);
        __syncthreads();
        for (int bb = t; bb < NBMAX; bb += 256)
            if (h[bb]) atomicAdd(&bcnt[bb], h[bb]);
    }
}

// ---------------- K2c: bucket-major edge reorder (packed (src<<16)|dst) -----
// global bucket offsets recomputed in-block (no bin_scan dispatch);
// gcur is a zero-based relative cursor.
__global__ __launch_bounds__(256) void bin_scatter(
    const int* __restrict__ src, const int* __restrict__ dst,
    const int* __restrict__ bcnt, int* __restrict__ gcur,
    unsigned* __restrict__ pairs_out, int e)
{
    __shared__ int hcnt[NBMAX], hstart[NBMAX], hcur[NBMAX], gpos[NBMAX], sgoff[NBMAX];
    __shared__ unsigned pairs[4096];
    int t = threadIdx.x;
    int base = blockIdx.x * 4096;
    int cnt = min(4096, e - base);
    for (int b = t; b < NBMAX; b += 256) hcnt[b] = 0;
    // in-block global bucket prefix (exclusive scan of bcnt)
    if (t < 64) {
        int v0 = bcnt[t * 8],     v1 = bcnt[t * 8 + 1], v2 = bcnt[t * 8 + 2], v3 = bcnt[t * 8 + 3];
        int v4 = bcnt[t * 8 + 4], v5 = bcnt[t * 8 + 5], v6 = bcnt[t * 8 + 6], v7 = bcnt[t * 8 + 7];
        int s = v0 + v1 + v2 + v3 + v4 + v5 + v6 + v7;
        int inc = s;
        #pragma unroll
        for (int st = 1; st < 64; st <<= 1) {
            int u = __shfl_up(inc, st);
            if (t >= st) inc += u;
        }
        int ex = inc - s;
        sgoff[t * 8] = ex;         ex += v0;
        sgoff[t * 8 + 1] = ex;     ex += v1;
        sgoff[t * 8 + 2] = ex;     ex += v2;
        sgoff[t * 8 + 3] = ex;     ex += v3;
        sgoff[t * 8 + 4] = ex;     ex += v4;
        sgoff[t * 8 + 5] = ex;     ex += v5;
        sgoff[t * 8 + 6] = ex;     ex += v6;
        sgoff[t * 8 + 7] = ex;
    }
    __syncthreads();

    int ls[16], ld[16];
    #pragma unroll
    for (int j = 0; j < 16; ++j) {
        int i = t + j * 256;
        ls[j] = 0; ld[j] = -1;
        if (i < cnt) {
            ls[j] = src[base + i];
            ld[j] = dst[base + i];
            atomicAdd(&hcnt[ld[j] >> BSHIFT], 1);
        }
    }
    __syncthreads();
    if (t < 64) {                             // exclusive prefix over 512 buckets
        int v[8]; int s = 0;
        #pragma unroll
        for (int j = 0; j < 8; ++j) { v[j] = hcnt[t * 8 + j]; s += v[j]; }
        int inc = s;
        #pragma unroll
        for (int st = 1; st < 64; st <<= 1) {
            int u = __shfl_up(inc, st);
            if (t >= st) inc += u;
        }
        int ex = inc - s;
        #pragma unroll
        for (int j = 0; j < 8; ++j) {
            hstart[t * 8 + j] = ex;
            hcur[t * 8 + j] = ex;
            ex += v[j];
        }
    }
    __syncthreads();
    #pragma unroll
    for (int j = 0; j < 16; ++j) {
        if (ld[j] >= 0) {
            int pos = atomicAdd(&hcur[ld[j] >> BSHIFT], 1);
            pairs[pos] = ((unsigned)ls[j] << 16) | (unsigned)ld[j];
        }
    }
    __syncthreads();
    for (int b = t; b < NBMAX; b += 256) {    // one global atomic per (block,bucket)
        int c = hcnt[b];
        if (c) gpos[b] = sgoff[b] + atomicAdd(&gcur[b], c);
    }
    __syncthreads();
    #pragma unroll
    for (int j = 0; j < 16; ++j) {
        int i = t + j * 256;
        if (i < cnt) {
            unsigned p = pairs[i];
            int b = (int)(p & 0xFFFFu) >> BSHIFT;   // bucket from packed dst
            pairs_out[gpos[b] + (i - hstart[b])] = p;
        }
    }
}

// ---------------- K2d: per-bucket CSR fill + offs ---------------------------
__global__ __launch_bounds__(128) void csr_fill(
    const unsigned* __restrict__ pairs, const int* __restrict__ bcnt,
    int* __restrict__ offs, int* __restrict__ csr, int n, int e)
{
    __shared__ int hist[128], pref[128], cur[128], sbase[1];
    int b = blockIdx.x, t = threadIdx.x;
    // in-block prefix of bcnt[0..b)
    if (t < 64) {
        int acc = 0;
        for (int k = t; k < b; k += 64) acc += bcnt[k];
        acc += __shfl_down(acc, 32); acc += __shfl_down(acc, 16);
        acc += __shfl_down(acc, 8);  acc += __shfl_down(acc, 4);
        acc += __shfl_down(acc, 2);  acc += __shfl_down(acc, 1);
        if (t == 0) sbase[0] = acc;
    }
    hist[t] = 0;
    __syncthreads();
    int base = sbase[0], cnt = bcnt[b];
    int node0 = b << BSHIFT;
    for (int i = t; i < cnt; i += 128)
        atomicAdd(&hist[pairs[base + i] & 127u], 1);
    __syncthreads();
    if (t < 64) {
        int v0 = hist[2 * t], v1 = hist[2 * t + 1];
        int s = v0 + v1, inc = s;
        #pragma unroll
        for (int st = 1; st < 64; st <<= 1) {
            int u = __shfl_up(inc, st);
            if (t >= st) inc += u;
        }
        int ex = inc - s;
        pref[2 * t] = ex;       cur[2 * t] = ex;
        pref[2 * t + 1] = ex + v0; cur[2 * t + 1] = ex + v0;
    }
    __syncthreads();
    int node = node0 + t;
    if (node < n) offs[node] = base + pref[t];
    if (b == gridDim.x - 1 && t == 0) offs[n] = e;
    for (int i = t; i < cnt; i += 128) {
        unsigned p = pairs[base + i];
        int pos = atomicAdd(&cur[p & 127u], 1);
        csr[base + pos] = (int)(p >> 16);
    }
}

// ---------------- K5: per-node multi-stat reduction (1 wave / node) ---------
// bf16 A rows (128B): half-wave per edge -> 2 edges per load; 16-edge unroll
// with NAMED SCALARS (8 independent gathers in flight, merge = 8 shuffles).
__global__ __launch_bounds__(256) void node_reduce(
    const unsigned* __restrict__ Ab, const float* __restrict__ Bp,
    const float* __restrict__ bm,
    const int* __restrict__ offs, const int* __restrict__ csr,
    unsigned* __restrict__ hbu, float* __restrict__ s1, float* __restrict__ s2,
    int n, int npad)
{
    int wid = threadIdx.x >> 6;
    int lane = threadIdx.x & 63;
    int node = blockIdx.x * 4 + wid;
    if (node >= npad) return;
    unsigned* hrow = hbu + (size_t)node * 128;   // 256 bf16 = 128 uints
    int l32 = lane & 31;
    int half = lane >> 5;
    int beg = 0, dg = 0;
    if (node < n) { beg = offs[node]; dg = offs[node + 1] - beg; }
    if (dg == 0) {
        if (half == 0) {
            hrow[l32] = 0u; hrow[32 + l32] = 0u; hrow[64 + l32] = 0u; hrow[96 + l32] = 0u;
        }
        if (lane == 0) { s1[node] = 0.f; s2[node] = 0.f; }
        return;
    }

    float s0 = 0.f, s1a = 0.f, ss0 = 0.f, ss1 = 0.f;
    float mx0 = -FLT_BIG, mx1 = -FLT_BIG, mn0 = FLT_BIG, mn1 = FLT_BIG;

#define ACC(u) { float v0 = bflo(u), v1 = bfhi(u);                          \
    s0 += v0; s1a += v1;                                                    \
    ss0 = fmaf(v0, v0, ss0); ss1 = fmaf(v1, v1, ss1);                       \
    mx0 = fmaxf(mx0, v0); mx1 = fmaxf(mx1, v1);                             \
    mn0 = fminf(mn0, v0); mn1 = fminf(mn1, v1); }
#define GA(sel) Ab[(size_t)(sel) * 32 + l32]

    int j = beg, end = beg + dg;
    for (; j + 15 < end; j += 16) {         // 16 edges, 8 independent gathers
        int i0 = csr[j],      i1 = csr[j + 1],  i2 = csr[j + 2],  i3 = csr[j + 3];
        int i4 = csr[j + 4],  i5 = csr[j + 5],  i6 = csr[j + 6],  i7 = csr[j + 7];
        int i8 = csr[j + 8],  i9 = csr[j + 9],  i10 = csr[j + 10], i11 = csr[j + 11];
        int i12 = csr[j + 12], i13 = csr[j + 13], i14 = csr[j + 14], i15 = csr[j + 15];
        unsigned u0 = GA(half ? i1 : i0);
        unsigned u1 = GA(half ? i3 : i2);
        unsigned u2 = GA(half ? i5 : i4);
        unsigned u3 = GA(half ? i7 : i6);
        unsigned u4 = GA(half ? i9 : i8);
        unsigned u5 = GA(half ? i11 : i10);
        unsigned u6 = GA(half ? i13 : i12);
        unsigned u7 = GA(half ? i15 : i14);
        ACC(u0); ACC(u1); ACC(u2); ACC(u3);
        ACC(u4); ACC(u5); ACC(u6); ACC(u7);
    }
    for (; j + 7 < end; j += 8) {           // 8 edges, 4 gathers
        int i0 = csr[j],     i1 = csr[j + 1], i2 = csr[j + 2], i3 = csr[j + 3];
        int i4 = csr[j + 4], i5 = csr[j + 5], i6 = csr[j + 6], i7 = csr[j + 7];
        unsigned u0 = GA(half ? i1 : i0);
        unsigned u1 = GA(half ? i3 : i2);
        unsigned u2 = GA(half ? i5 : i4);
        unsigned u3 = GA(half ? i7 : i6);
        ACC(u0); ACC(u1); ACC(u2); ACC(u3);
    }
    for (; j + 1 < end; j += 2) {
        int i0 = csr[j], i1 = csr[j + 1];
        unsigned u0 = GA(half ? i1 : i0);
        ACC(u0);
    }
    if (j < end) {                          // odd tail: half 0 only
        unsigned u0 = GA(csr[j]);
        if (half == 0) ACC(u0);
    }
#undef GA
#undef ACC

    s0 += __shfl_xor(s0, 32);  s1a += __shfl_xor(s1a, 32);
    ss0 += __shfl_xor(ss0, 32); ss1 += __shfl_xor(ss1, 32);
    mx0 = fmaxf(mx0, __shfl_xor(mx0, 32)); mx1 = fmaxf(mx1, __shfl_xor(mx1, 32));
    mn0 = fminf(mn0, __shfl_xor(mn0, 32)); mn1 = fminf(mn1, __shfl_xor(mn1, 32));

    float fd = (float)dg, inv = 1.0f / fd;
    float2 bv = *(const float2*)(Bp + (size_t)node * 64 + 2 * l32);
    float2 bmv = *(const float2*)(bm + 2 * l32);
    float bn0 = bv.x + bmv.x, bn1 = bv.y + bmv.y;
    float ma0 = s0 * inv, ma1 = s1a * inv;
    float var0 = ss0 * inv - ma0 * ma0; if (var0 < 0.f) var0 = 0.f;
    float var1 = ss1 * inv - ma1 * ma1; if (var1 < 0.f) var1 = 0.f;
    float sd0 = sqrtf(var0 + MOM_EPS_C), sd1 = sqrtf(var1 + MOM_EPS_C);

    if (half == 0) {
        hrow[l32]      = pack2(ma0 + bn0, ma1 + bn1);
        hrow[32 + l32] = pack2(mx0 + bn0, mx1 + bn1);
        hrow[64 + l32] = pack2(mn0 + bn0, mn1 + bn1);
        hrow[96 + l32] = pack2(sd0, sd1);
    }
    if (lane == 0) {
        float logD = logf(fd + 1.0f);
        s1[node] = logD / DELTA_C;
        s2[node] = DELTA_C / logD;
    }
}

// ---------------- K6: MFMA update GEMM + fused BN column stats --------------
__global__ __launch_bounds__(256) void gemm_mfma(
    const short* __restrict__ xb, const short* __restrict__ hb,
    const float* __restrict__ s1p, const float* __restrict__ s2p,
    const short* __restrict__ Wup, const float* __restrict__ bu,
    float* __restrict__ z, float* __restrict__ bnacc, int n, float snorm)
{
    __shared__ float bnl[4][2][64];
    int t = threadIdx.x;
    int lane = t & 63, w = t >> 6;
    int rb = blockIdx.x * 128 + w * 32;
    int r16 = lane & 15, kg = lane >> 4;

    f32x4 accx[2][4] = {};
    f32x4 acc1[2][4] = {};
    f32x4 acc2[2][4] = {};
    f32x4 acc3[2][4] = {};

    const short* xr0 = xb + (size_t)(rb + r16) * 64 + kg * 8;
    const short* xr1 = xr0 + 16 * 64;

    #pragma unroll
    for (int kc = 0; kc < 2; ++kc) {
        bf16x8 a0 = *(const bf16x8*)(xr0 + kc * 32);
        bf16x8 a1 = *(const bf16x8*)(xr1 + kc * 32);
        #pragma unroll
        for (int c = 0; c < 4; ++c) {
            bf16x8 b = *(const bf16x8*)(Wup + (size_t)((kc * 4 + c) * 64 + lane) * 8);
            accx[0][c] = __builtin_amdgcn_mfma_f32_16x16x32_bf16(a0, b, accx[0][c], 0, 0, 0);
            accx[1][c] = __builtin_amdgcn_mfma_f32_16x16x32_bf16(a1, b, accx[1][c], 0, 0, 0);
        }
    }

    const short* hr0 = hb + (size_t)(rb + r16) * 256 + kg * 8;
    const short* hr1 = hr0 + 16 * 256;

    #pragma unroll 1
    for (int kh = 0; kh < 8; ++kh) {
        bf16x8 a0 = *(const bf16x8*)(hr0 + kh * 32);
        bf16x8 a1 = *(const bf16x8*)(hr1 + kh * 32);
        #pragma unroll
        for (int c = 0; c < 4; ++c) {
            bf16x8 b1 = *(const bf16x8*)(Wup + (size_t)(((2  + kh) * 4 + c) * 64 + lane) * 8);
            bf16x8 b2 = *(const bf16x8*)(Wup + (size_t)(((10 + kh) * 4 + c) * 64 + lane) * 8);
            bf16x8 b3 = *(const bf16x8*)(Wup + (size_t)(((18 + kh) * 4 + c) * 64 + lane) * 8);
            acc1[0][c] = __builtin_amdgcn_mfma_f32_16x16x32_bf16(a0, b1, acc1[0][c], 0, 0, 0);
            acc1[1][c] = __builtin_amdgcn_mfma_f32_16x16x32_bf16(a1, b1, acc1[1][c], 0, 0, 0);
            acc2[0][c] = __builtin_amdgcn_mfma_f32_16x16x32_bf16(a0, b2, acc2[0][c], 0, 0, 0);
            acc2[1][c] = __builtin_amdgcn_mfma_f32_16x16x32_bf16(a1, b2, acc2[1][c], 0, 0, 0);
            acc3[0][c] = __builtin_amdgcn_mfma_f32_16x16x32_bf16(a0, b3, acc3[0][c], 0, 0, 0);
            acc3[1][c] = __builtin_amdgcn_mfma_f32_16x16x32_bf16(a1, b3, acc3[1][c], 0, 0, 0);
        }
    }

    // epilogue: C/D frag layout col=lane&15, row=(lane>>4)*4+reg  [verified]
    float cs[4] = {}, css[4] = {};            // per-thread BN partials (4 cols)
    #pragma unroll
    for (int s = 0; s < 2; ++s) {
        int r0 = rb + s * 16 + kg * 4;
        float s1v[4], s2v[4];
        #pragma unroll
        for (int r = 0; r < 4; ++r) { s1v[r] = s1p[r0 + r]; s2v[r] = s2p[r0 + r]; }
        #pragma unroll
        for (int c = 0; c < 4; ++c) {
            int col = c * 16 + r16;
            float bval = bu[col];
            #pragma unroll
            for (int r = 0; r < 4; ++r) {
                int row = r0 + r;
                if (row < n) {
                    float v = (accx[s][c][r] + acc1[s][c][r]
                            + s1v[r] * acc2[s][c][r] + s2v[r] * acc3[s][c][r] + bval) * snorm;
                    z[(size_t)row * 64 + col] = v;
                    cs[c] += v;
                    css[c] = fmaf(v, v, css[c]);
                }
            }
        }
    }
    // butterfly over kg (lanes xor 16,32): all lanes end with the kg-sum
    #pragma unroll
    for (int c = 0; c < 4; ++c) {
        float a = cs[c];  a += __shfl_xor(a, 16); a += __shfl_xor(a, 32); cs[c] = a;
        float b = css[c]; b += __shfl_xor(b, 16); b += __shfl_xor(b, 32); css[c] = b;
    }
    if (lane < 16) {
        #pragma unroll
        for (int c = 0; c < 4; ++c) {
            bnl[w][0][c * 16 + lane] = cs[c];
            bnl[w][1][c * 16 + lane] = css[c];
        }
    }
    __syncthreads();
    if (t < 128) {
        int st = t >> 6, cc = t & 63;
        float tot = bnl[0][st][cc] + bnl[1][st][cc] + bnl[2][st][cc] + bnl[3][st][cc];
        atomicAdd(&bnacc[st * 64 + cc], tot);
    }
}

// ---------------- K8: BN normalize (in place on d_out, float4/thread) -------
__global__ __launch_bounds__(256) void bn_apply(
    float* __restrict__ z, const float* __restrict__ acc,
    const float* __restrict__ gamma, const float* __restrict__ beta, int n)
{
    float inv_n = 1.0f / (float)n;
    int tid = blockIdx.x * 256 + threadIdx.x;
    int c0 = (tid * 4) & 63;                    // fixed columns for this thread
    float sc[4], sh[4];
    #pragma unroll
    for (int k = 0; k < 4; ++k) {
        int c = c0 + k;
        float mu = acc[c] * inv_n;
        float var = acc[64 + c] * inv_n - mu * mu;
        if (var < 0.f) var = 0.f;
        float inv = rsqrtf(var + BN_EPS_C) * gamma[c];
        sc[k] = inv;
        sh[k] = beta[c] - mu * inv;
    }
    int total4 = n * 16;                        // n*64 / 4
    int stride = gridDim.x * 256;               // *4 floats: multiple of 64 ✓
    for (int i = tid; i < total4; i += stride) {
        float4 v = *(float4*)&z[(size_t)i * 4];
        v.x = fmaf(v.x, sc[0], sh[0]);
        v.y = fmaf(v.y, sc[1], sh[1]);
        v.z = fmaf(v.z, sc[2], sh[2]);
        v.w = fmaf(v.w, sc[3], sh[3]);
        *(float4*)&z[(size_t)i * 4] = v;
    }
}

extern "C" void kernel_launch(void* const* d_in, const int* in_sizes, int n_in,
                              void* d_out, int out_size, void* d_ws, size_t ws_size,
                              hipStream_t stream)
{
    const float* x     = (const float*)d_in[0];
    const float* Wm    = (const float*)d_in[1];
    const float* bm    = (const float*)d_in[2];
    const float* Wu    = (const float*)d_in[3];
    const float* bu    = (const float*)d_in[4];
    const float* gamma = (const float*)d_in[5];
    const float* beta  = (const float*)d_in[6];
    const int*   src   = (const int*)d_in[7];
    const int*   dst   = (const int*)d_in[8];

    int n = in_sizes[0] / 64;
    int e = in_sizes[7];
    int npad = ((n + 127) / 128) * 128;
    int nb = (n + 127) >> BSHIFT;          // buckets (<=512 for n<=65535)
    float* z = (float*)d_out;

    char* w = (char*)d_ws;
    size_t off = 0;
    auto take = [&](size_t bytes) -> void* {
        void* p = w + off;
        off = (off + bytes + 255) & ~(size_t)255;
        return p;
    };
    unsigned* Ab    = (unsigned*)take((size_t)npad * 32 * sizeof(unsigned));
    float*    B     = (float*)take((size_t)n * 64 * sizeof(float));
    unsigned* xbu   = (unsigned*)take((size_t)npad * 32 * sizeof(unsigned));
    unsigned* hbu   = (unsigned*)take((size_t)npad * 128 * sizeof(unsigned));
    float*    s1    = (float*)take((size_t)npad * sizeof(float));
    float*    s2    = (float*)take((size_t)npad * sizeof(float));
    short*    Wup   = (short*)take((size_t)26 * 4 * 64 * 8 * sizeof(short));
    int*      offs  = (int*)take((size_t)(n + 1) * sizeof(int));
    int*      csr   = (int*)take((size_t)e * sizeof(int));
    unsigned* prs   = (unsigned*)take((size_t)e * sizeof(unsigned));
    int*      bcnt  = (int*)take((size_t)NBMAX * sizeof(int));
    int*      gcur  = (int*)take((size_t)NBMAX * sizeof(int));
    float*    bnacc = (float*)take(128 * sizeof(float));

    (void)n_in; (void)out_size; (void)ws_size;

    int nb_rows64 = npad / 64;
    int nb_chunk = (e + 4095) / 4096;

    repack_wu<<<26, 256, 0, stream>>>(Wu, Wup, bcnt, gcur, bnacc);
    proj_ab<<<nb_rows64, 256, 0, stream>>>(x, Wm, Ab, B, xbu, n, dst, bcnt, e, nb_chunk);
    bin_scatter<<<nb_chunk, 256, 0, stream>>>(src, dst, bcnt, gcur, prs, e);
    csr_fill<<<nb, 128, 0, stream>>>(prs, bcnt, offs, csr, n, e);
    node_reduce<<<(npad + 3) / 4, 256, 0, stream>>>(Ab, B, bm, offs, csr, hbu, s1, s2, n, npad);

    float snorm = (float)(1.0 / sqrt((double)n));
    gemm_mfma<<<npad / 128, 256, 0, stream>>>((const short*)xbu, (const short*)hbu,
                                              s1, s2, Wup, bu, z, bnacc, n, snorm);

    bn_apply<<<512, 256, 0, stream>>>(z, bnacc, gamma, beta, n);
}

// Round 10
// 109.326 us; speedup vs baseline: 1.3675x; 1.1025x over previous
//
#include <hip/hip_runtime.h>
#include <hip/hip_bf16.h>

// PNAConvTower: h' = BN( snorm * ([x, PNA_aggr(x)] @ Wu + bu) )
// msg[e] = A[src[e]] + B[dst[e]] + bm   where A = x@Wm[:64], B = x@Wm[64:]
// Stats are shift-invariant: reduce over A[src] only, add (B[dst]+bm) at the end.
// CSR via 2-level counting sort (bucket = dst>>7); edge packed (src<<16)|dst
// (requires n <= 65535; here n = 50000).
// z = x@W0 + h@W1 + s1*(h@W2) + s2*(h@W3) + bu  (scalers folded, bf16 MFMA)
// R10: proj is now an MFMA kernel ([A|B] = x @ [Wm_top|Wm_bot], 128 cols out),
// with Wu-repack + zero-inits folded in. 6 dispatches total.
// node_reduce lessons: (R6) no private arrays — promote-alloca puts them in
// LDS; (R8) keep the cross-lane merge NARROW (half-wave + 8 shuffles).

#define DELTA_C 2.83f
#define BN_EPS_C 1e-5f
#define MOM_EPS_C 1e-30f
#define FLT_BIG 3.402823466e38f
#define BSHIFT 7            // 128 nodes per bucket
#define NBMAX 512           // supports n <= 65535

typedef __attribute__((ext_vector_type(8))) short bf16x8;   // 8 bf16 (4 VGPRs)
typedef __attribute__((ext_vector_type(4))) float f32x4;    // MFMA C/D frag

static __device__ __forceinline__ unsigned short f2bf(float f) {
    unsigned u = __float_as_uint(f);
    unsigned r = (u + 0x7FFFu + ((u >> 16) & 1u)) >> 16;    // RNE
    return (unsigned short)r;
}
static __device__ __forceinline__ unsigned pack2(float a, float b) {
    return (unsigned)f2bf(a) | ((unsigned)f2bf(b) << 16);
}
static __device__ __forceinline__ float bflo(unsigned u) { return __uint_as_float(u << 16); }
static __device__ __forceinline__ float bfhi(unsigned u) { return __uint_as_float(u & 0xFFFF0000u); }

// ---------------- K1: MFMA projection -------------------------------------
// [A|B](128x128) = bf16(x)(128x64) @ bf16([Wm_top|Wm_bot])(64x128)
// + xb=bf16(x) out, + fused bucket histogram, + Wu repack (blocks 0..25),
// + zero-init (block 0).
__global__ __launch_bounds__(256) void proj_mfma(
    const float* __restrict__ x, const float* __restrict__ Wm,
    unsigned* __restrict__ Ab, float* __restrict__ B,
    unsigned* __restrict__ xbu, int n,
    const int* __restrict__ dst, int* __restrict__ bcnt, int e, int nb_chunk,
    const float* __restrict__ Wu, short* __restrict__ Wup,
    int* __restrict__ gcur, float* __restrict__ bnacc)
{
    __shared__ short xs[128][72];             // row stride 144B: 2-way (free) aliasing
    __shared__ short wc[2][8][64][8];         // [kc][cfrag][lane][i] bf16 frag order
    __shared__ int h[NBMAX];
    int t = threadIdx.x;
    int row0 = blockIdx.x * 128;

    if (blockIdx.x == 0) {                    // fold in tiny zero-fills
        bcnt[t] = 0; bcnt[t + 256] = 0;
        gcur[t] = 0; gcur[t + 256] = 0;
        if (t < 128) bnacc[t] = 0.f;
    }

    // Wu repack (blocks 0..25; 26*256 == 26*4*64 lane-groups). Layout as R1:
    // Wup[chunk(26)][cfrag(4)][lane(64)][i(8)], k = chunk*32+(lane>>4)*8+i,
    // col = cfrag*16+(lane&15).
    if (blockIdx.x < 26) {
        int idx = blockIdx.x * 256 + t;
        int lane2 = idx & 63, c2 = (idx >> 6) & 3, kc2 = idx >> 8;
        int kbase = kc2 * 32 + (lane2 >> 4) * 8;
        int col = c2 * 16 + (lane2 & 15);
        unsigned short o[8];
        #pragma unroll
        for (int i = 0; i < 8; ++i)
            o[i] = f2bf(Wu[(size_t)(kbase + i) * 64 + col]);
        uint4 u;
        u.x = o[0] | ((unsigned)o[1] << 16);
        u.y = o[2] | ((unsigned)o[3] << 16);
        u.z = o[4] | ((unsigned)o[5] << 16);
        u.w = o[6] | ((unsigned)o[7] << 16);
        *(uint4*)(Wup + (size_t)idx * 8) = u;
    }

    // stage combined Wm (64K x 128N) into wc, same frag convention as Wup
    for (int g = t; g < 1024; g += 256) {
        int kc = g >> 9, c = (g >> 6) & 7, lane = g & 63;
        int kb = kc * 32 + (lane >> 4) * 8;
        int cc = c * 16 + (lane & 15);
        const float* wsrc = (cc < 64) ? (Wm + (size_t)kb * 64 + cc)
                                      : (Wm + (size_t)(64 + kb) * 64 + (cc - 64));
        unsigned short o0 = f2bf(wsrc[0]);
        unsigned short o1 = f2bf(wsrc[64]);
        unsigned short o2 = f2bf(wsrc[128]);
        unsigned short o3 = f2bf(wsrc[192]);
        unsigned short o4 = f2bf(wsrc[256]);
        unsigned short o5 = f2bf(wsrc[320]);
        unsigned short o6 = f2bf(wsrc[384]);
        unsigned short o7 = f2bf(wsrc[448]);
        uint4 u;
        u.x = o0 | ((unsigned)o1 << 16);
        u.y = o2 | ((unsigned)o3 << 16);
        u.z = o4 | ((unsigned)o5 << 16);
        u.w = o6 | ((unsigned)o7 << 16);
        *(uint4*)&wc[kc][c][lane][0] = u;
    }

    // stage x rows: 2 threads/row, 32 f32 each -> bf16 to LDS + xbu
    {
        int r = t >> 1, hf = t & 1;
        int row = row0 + r;
        float4 f0 = {}, f1 = {}, f2 = {}, f3 = {}, f4 = {}, f5 = {}, f6 = {}, f7 = {};
        if (row < n) {
            const float4* xr = (const float4*)(x + (size_t)row * 64 + hf * 32);
            f0 = xr[0]; f1 = xr[1]; f2 = xr[2]; f3 = xr[3];
            f4 = xr[4]; f5 = xr[5]; f6 = xr[6]; f7 = xr[7];
        }
        uint4 ua, ub, uc, ud;
        ua.x = pack2(f0.x, f0.y); ua.y = pack2(f0.z, f0.w);
        ua.z = pack2(f1.x, f1.y); ua.w = pack2(f1.z, f1.w);
        ub.x = pack2(f2.x, f2.y); ub.y = pack2(f2.z, f2.w);
        ub.z = pack2(f3.x, f3.y); ub.w = pack2(f3.z, f3.w);
        uc.x = pack2(f4.x, f4.y); uc.y = pack2(f4.z, f4.w);
        uc.z = pack2(f5.x, f5.y); uc.w = pack2(f5.z, f5.w);
        ud.x = pack2(f6.x, f6.y); ud.y = pack2(f6.z, f6.w);
        ud.z = pack2(f7.x, f7.y); ud.w = pack2(f7.z, f7.w);
        uint4* xd = (uint4*)(xbu + (size_t)row * 32 + hf * 16);
        xd[0] = ua; xd[1] = ub; xd[2] = uc; xd[3] = ud;
        uint4* xl = (uint4*)&xs[r][hf * 32];
        xl[0] = ua; xl[1] = ub; xl[2] = uc; xl[3] = ud;
    }
    __syncthreads();

    // MFMA: wave w -> rows w*32..+31 (2 strips of 16) x 128 cols (8 cfrags)
    int lane = t & 63, w = t >> 6;
    int r16 = lane & 15, kg = lane >> 4;
    int wr0 = w * 32;
    f32x4 acc0[8] = {};
    f32x4 acc1[8] = {};
    #pragma unroll
    for (int kc = 0; kc < 2; ++kc) {
        bf16x8 a0 = *(const bf16x8*)&xs[wr0 + r16][kc * 32 + kg * 8];
        bf16x8 a1 = *(const bf16x8*)&xs[wr0 + 16 + r16][kc * 32 + kg * 8];
        #pragma unroll
        for (int c = 0; c < 8; ++c) {
            bf16x8 b = *(const bf16x8*)&wc[kc][c][lane][0];
            acc0[c] = __builtin_amdgcn_mfma_f32_16x16x32_bf16(a0, b, acc0[c], 0, 0, 0);
            acc1[c] = __builtin_amdgcn_mfma_f32_16x16x32_bf16(a1, b, acc1[c], 0, 0, 0);
        }
    }
    // epilogue: C/D col=c*16+r16, row=(kg*4+r) within strip [verified layout]
    short* AbS = (short*)Ab;
    #pragma unroll
    for (int c = 0; c < 8; ++c) {
        #pragma unroll
        for (int r = 0; r < 4; ++r) {
            int rowA = row0 + wr0 + kg * 4 + r;
            int rowB = rowA + 16;
            if (c < 4) {
                int col = c * 16 + r16;
                if (rowA < n) AbS[(size_t)rowA * 64 + col] = (short)f2bf(acc0[c][r]);
                if (rowB < n) AbS[(size_t)rowB * 64 + col] = (short)f2bf(acc1[c][r]);
            } else {
                int col = (c - 4) * 16 + r16;
                if (rowA < n) B[(size_t)rowA * 64 + col] = acc0[c][r];
                if (rowB < n) B[(size_t)rowB * 64 + col] = acc1[c][r];
            }
        }
    }

    // fused bucket histogram (stride loop; barriers block-uniform)
    for (int ch = blockIdx.x; ch < nb_chunk; ch += gridDim.x) {
        __syncthreads();
        for (int bb = t; bb < NBMAX; bb += 256) h[bb] = 0;
        __syncthreads();
        int base = ch * 4096;
        int cnt = min(4096, e - base);
        for (int i = t; i < cnt; i += 256)
            atomicAdd(&h[dst[base + i] >> BSHIFT], 1);
        __syncthreads();
        for (int bb = t; bb < NBMAX; bb += 256)
            if (h[bb]) atomicAdd(&bcnt[bb], h[bb]);
    }
}

// ---------------- K2c: bucket-major edge reorder (packed (src<<16)|dst) -----
__global__ __launch_bounds__(256) void bin_scatter(
    const int* __restrict__ src, const int* __restrict__ dst,
    const int* __restrict__ bcnt, int* __restrict__ gcur,
    unsigned* __restrict__ pairs_out, int e)
{
    __shared__ int hcnt[NBMAX], hstart[NBMAX], hcur[NBMAX], gpos[NBMAX], sgoff[NBMAX];
    __shared__ unsigned pairs[4096];
    int t = threadIdx.x;
    int base = blockIdx.x * 4096;
    int cnt = min(4096, e - base);
    for (int b = t; b < NBMAX; b += 256) hcnt[b] = 0;
    // in-block global bucket prefix (exclusive scan of bcnt)
    if (t < 64) {
        int v0 = bcnt[t * 8],     v1 = bcnt[t * 8 + 1], v2 = bcnt[t * 8 + 2], v3 = bcnt[t * 8 + 3];
        int v4 = bcnt[t * 8 + 4], v5 = bcnt[t * 8 + 5], v6 = bcnt[t * 8 + 6], v7 = bcnt[t * 8 + 7];
        int s = v0 + v1 + v2 + v3 + v4 + v5 + v6 + v7;
        int inc = s;
        #pragma unroll
        for (int st = 1; st < 64; st <<= 1) {
            int u = __shfl_up(inc, st);
            if (t >= st) inc += u;
        }
        int ex = inc - s;
        sgoff[t * 8] = ex;         ex += v0;
        sgoff[t * 8 + 1] = ex;     ex += v1;
        sgoff[t * 8 + 2] = ex;     ex += v2;
        sgoff[t * 8 + 3] = ex;     ex += v3;
        sgoff[t * 8 + 4] = ex;     ex += v4;
        sgoff[t * 8 + 5] = ex;     ex += v5;
        sgoff[t * 8 + 6] = ex;     ex += v6;
        sgoff[t * 8 + 7] = ex;
    }
    __syncthreads();

    int ls[16], ld[16];
    #pragma unroll
    for (int j = 0; j < 16; ++j) {
        int i = t + j * 256;
        ls[j] = 0; ld[j] = -1;
        if (i < cnt) {
            ls[j] = src[base + i];
            ld[j] = dst[base + i];
            atomicAdd(&hcnt[ld[j] >> BSHIFT], 1);
        }
    }
    __syncthreads();
    if (t < 64) {                             // exclusive prefix over 512 buckets
        int v[8]; int s = 0;
        #pragma unroll
        for (int j = 0; j < 8; ++j) { v[j] = hcnt[t * 8 + j]; s += v[j]; }
        int inc = s;
        #pragma unroll
        for (int st = 1; st < 64; st <<= 1) {
            int u = __shfl_up(inc, st);
            if (t >= st) inc += u;
        }
        int ex = inc - s;
        #pragma unroll
        for (int j = 0; j < 8; ++j) {
            hstart[t * 8 + j] = ex;
            hcur[t * 8 + j] = ex;
            ex += v[j];
        }
    }
    __syncthreads();
    #pragma unroll
    for (int j = 0; j < 16; ++j) {
        if (ld[j] >= 0) {
            int pos = atomicAdd(&hcur[ld[j] >> BSHIFT], 1);
            pairs[pos] = ((unsigned)ls[j] << 16) | (unsigned)ld[j];
        }
    }
    __syncthreads();
    for (int b = t; b < NBMAX; b += 256) {    // one global atomic per (block,bucket)
        int c = hcnt[b];
        if (c) gpos[b] = sgoff[b] + atomicAdd(&gcur[b], c);
    }
    __syncthreads();
    #pragma unroll
    for (int j = 0; j < 16; ++j) {
        int i = t + j * 256;
        if (i < cnt) {
            unsigned p = pairs[i];
            int b = (int)(p & 0xFFFFu) >> BSHIFT;   // bucket from packed dst
            pairs_out[gpos[b] + (i - hstart[b])] = p;
        }
    }
}

// ---------------- K2d: per-bucket CSR fill + offs ---------------------------
__global__ __launch_bounds__(128) void csr_fill(
    const unsigned* __restrict__ pairs, const int* __restrict__ bcnt,
    int* __restrict__ offs, int* __restrict__ csr, int n, int e)
{
    __shared__ int hist[128], pref[128], cur[128], sbase[1];
    int b = blockIdx.x, t = threadIdx.x;
    // in-block prefix of bcnt[0..b)
    if (t < 64) {
        int acc = 0;
        for (int k = t; k < b; k += 64) acc += bcnt[k];
        acc += __shfl_down(acc, 32); acc += __shfl_down(acc, 16);
        acc += __shfl_down(acc, 8);  acc += __shfl_down(acc, 4);
        acc += __shfl_down(acc, 2);  acc += __shfl_down(acc, 1);
        if (t == 0) sbase[0] = acc;
    }
    hist[t] = 0;
    __syncthreads();
    int base = sbase[0], cnt = bcnt[b];
    int node0 = b << BSHIFT;
    for (int i = t; i < cnt; i += 128)
        atomicAdd(&hist[pairs[base + i] & 127u], 1);
    __syncthreads();
    if (t < 64) {
        int v0 = hist[2 * t], v1 = hist[2 * t + 1];
        int s = v0 + v1, inc = s;
        #pragma unroll
        for (int st = 1; st < 64; st <<= 1) {
            int u = __shfl_up(inc, st);
            if (t >= st) inc += u;
        }
        int ex = inc - s;
        pref[2 * t] = ex;       cur[2 * t] = ex;
        pref[2 * t + 1] = ex + v0; cur[2 * t + 1] = ex + v0;
    }
    __syncthreads();
    int node = node0 + t;
    if (node < n) offs[node] = base + pref[t];
    if (b == gridDim.x - 1 && t == 0) offs[n] = e;
    for (int i = t; i < cnt; i += 128) {
        unsigned p = pairs[base + i];
        int pos = atomicAdd(&cur[p & 127u], 1);
        csr[base + pos] = (int)(p >> 16);
    }
}

// ---------------- K5: per-node multi-stat reduction (1 wave / node) ---------
// bf16 A rows (128B): half-wave per edge -> 2 edges per load; 16-edge unroll
// with NAMED SCALARS (8 independent gathers in flight, merge = 8 shuffles).
__global__ __launch_bounds__(256) void node_reduce(
    const unsigned* __restrict__ Ab, const float* __restrict__ Bp,
    const float* __restrict__ bm,
    const int* __restrict__ offs, const int* __restrict__ csr,
    unsigned* __restrict__ hbu, float* __restrict__ s1, float* __restrict__ s2,
    int n, int npad)
{
    int wid = threadIdx.x >> 6;
    int lane = threadIdx.x & 63;
    int node = blockIdx.x * 4 + wid;
    if (node >= npad) return;
    unsigned* hrow = hbu + (size_t)node * 128;   // 256 bf16 = 128 uints
    int l32 = lane & 31;
    int half = lane >> 5;
    int beg = 0, dg = 0;
    if (node < n) { beg = offs[node]; dg = offs[node + 1] - beg; }
    if (dg == 0) {
        if (half == 0) {
            hrow[l32] = 0u; hrow[32 + l32] = 0u; hrow[64 + l32] = 0u; hrow[96 + l32] = 0u;
        }
        if (lane == 0) { s1[node] = 0.f; s2[node] = 0.f; }
        return;
    }

    float s0 = 0.f, s1a = 0.f, ss0 = 0.f, ss1 = 0.f;
    float mx0 = -FLT_BIG, mx1 = -FLT_BIG, mn0 = FLT_BIG, mn1 = FLT_BIG;

#define ACC(u) { float v0 = bflo(u), v1 = bfhi(u);                          \
    s0 += v0; s1a += v1;                                                    \
    ss0 = fmaf(v0, v0, ss0); ss1 = fmaf(v1, v1, ss1);                       \
    mx0 = fmaxf(mx0, v0); mx1 = fmaxf(mx1, v1);                             \
    mn0 = fminf(mn0, v0); mn1 = fminf(mn1, v1); }
#define GA(sel) Ab[(size_t)(sel) * 32 + l32]

    int j = beg, end = beg + dg;
    for (; j + 15 < end; j += 16) {         // 16 edges, 8 independent gathers
        int i0 = csr[j],      i1 = csr[j + 1],  i2 = csr[j + 2],  i3 = csr[j + 3];
        int i4 = csr[j + 4],  i5 = csr[j + 5],  i6 = csr[j + 6],  i7 = csr[j + 7];
        int i8 = csr[j + 8],  i9 = csr[j + 9],  i10 = csr[j + 10], i11 = csr[j + 11];
        int i12 = csr[j + 12], i13 = csr[j + 13], i14 = csr[j + 14], i15 = csr[j + 15];
        unsigned u0 = GA(half ? i1 : i0);
        unsigned u1 = GA(half ? i3 : i2);
        unsigned u2 = GA(half ? i5 : i4);
        unsigned u3 = GA(half ? i7 : i6);
        unsigned u4 = GA(half ? i9 : i8);
        unsigned u5 = GA(half ? i11 : i10);
        unsigned u6 = GA(half ? i13 : i12);
        unsigned u7 = GA(half ? i15 : i14);
        ACC(u0); ACC(u1); ACC(u2); ACC(u3);
        ACC(u4); ACC(u5); ACC(u6); ACC(u7);
    }
    for (; j + 7 < end; j += 8) {           // 8 edges, 4 gathers
        int i0 = csr[j],     i1 = csr[j + 1], i2 = csr[j + 2], i3 = csr[j + 3];
        int i4 = csr[j + 4], i5 = csr[j + 5], i6 = csr[j + 6], i7 = csr[j + 7];
        unsigned u0 = GA(half ? i1 : i0);
        unsigned u1 = GA(half ? i3 : i2);
        unsigned u2 = GA(half ? i5 : i4);
        unsigned u3 = GA(half ? i7 : i6);
        ACC(u0); ACC(u1); ACC(u2); ACC(u3);
    }
    for (; j + 1 < end; j += 2) {
        int i0 = csr[j], i1 = csr[j + 1];
        unsigned u0 = GA(half ? i1 : i0);
        ACC(u0);
    }
    if (j < end) {                          // odd tail: half 0 only
        unsigned u0 = GA(csr[j]);
        if (half == 0) ACC(u0);
    }
#undef GA
#undef ACC

    s0 += __shfl_xor(s0, 32);  s1a += __shfl_xor(s1a, 32);
    ss0 += __shfl_xor(ss0, 32); ss1 += __shfl_xor(ss1, 32);
    mx0 = fmaxf(mx0, __shfl_xor(mx0, 32)); mx1 = fmaxf(mx1, __shfl_xor(mx1, 32));
    mn0 = fminf(mn0, __shfl_xor(mn0, 32)); mn1 = fminf(mn1, __shfl_xor(mn1, 32));

    float fd = (float)dg, inv = 1.0f / fd;
    float2 bv = *(const float2*)(Bp + (size_t)node * 64 + 2 * l32);
    float2 bmv = *(const float2*)(bm + 2 * l32);
    float bn0 = bv.x + bmv.x, bn1 = bv.y + bmv.y;
    float ma0 = s0 * inv, ma1 = s1a * inv;
    float var0 = ss0 * inv - ma0 * ma0; if (var0 < 0.f) var0 = 0.f;
    float var1 = ss1 * inv - ma1 * ma1; if (var1 < 0.f) var1 = 0.f;
    float sd0 = sqrtf(var0 + MOM_EPS_C), sd1 = sqrtf(var1 + MOM_EPS_C);

    if (half == 0) {
        hrow[l32]      = pack2(ma0 + bn0, ma1 + bn1);
        hrow[32 + l32] = pack2(mx0 + bn0, mx1 + bn1);
        hrow[64 + l32] = pack2(mn0 + bn0, mn1 + bn1);
        hrow[96 + l32] = pack2(sd0, sd1);
    }
    if (lane == 0) {
        float logD = logf(fd + 1.0f);
        s1[node] = logD / DELTA_C;
        s2[node] = DELTA_C / logD;
    }
}

// ---------------- K6: MFMA update GEMM + fused BN column stats --------------
__global__ __launch_bounds__(256) void gemm_mfma(
    const short* __restrict__ xb, const short* __restrict__ hb,
    const float* __restrict__ s1p, const float* __restrict__ s2p,
    const short* __restrict__ Wup, const float* __restrict__ bu,
    float* __restrict__ z, float* __restrict__ bnacc, int n, float snorm)
{
    __shared__ float bnl[4][2][64];
    int t = threadIdx.x;
    int lane = t & 63, w = t >> 6;
    int rb = blockIdx.x * 128 + w * 32;
    int r16 = lane & 15, kg = lane >> 4;

    f32x4 accx[2][4] = {};
    f32x4 acc1[2][4] = {};
    f32x4 acc2[2][4] = {};
    f32x4 acc3[2][4] = {};

    const short* xr0 = xb + (size_t)(rb + r16) * 64 + kg * 8;
    const short* xr1 = xr0 + 16 * 64;

    #pragma unroll
    for (int kc = 0; kc < 2; ++kc) {
        bf16x8 a0 = *(const bf16x8*)(xr0 + kc * 32);
        bf16x8 a1 = *(const bf16x8*)(xr1 + kc * 32);
        #pragma unroll
        for (int c = 0; c < 4; ++c) {
            bf16x8 b = *(const bf16x8*)(Wup + (size_t)((kc * 4 + c) * 64 + lane) * 8);
            accx[0][c] = __builtin_amdgcn_mfma_f32_16x16x32_bf16(a0, b, accx[0][c], 0, 0, 0);
            accx[1][c] = __builtin_amdgcn_mfma_f32_16x16x32_bf16(a1, b, accx[1][c], 0, 0, 0);
        }
    }

    const short* hr0 = hb + (size_t)(rb + r16) * 256 + kg * 8;
    const short* hr1 = hr0 + 16 * 256;

    #pragma unroll 1
    for (int kh = 0; kh < 8; ++kh) {
        bf16x8 a0 = *(const bf16x8*)(hr0 + kh * 32);
        bf16x8 a1 = *(const bf16x8*)(hr1 + kh * 32);
        #pragma unroll
        for (int c = 0; c < 4; ++c) {
            bf16x8 b1 = *(const bf16x8*)(Wup + (size_t)(((2  + kh) * 4 + c) * 64 + lane) * 8);
            bf16x8 b2 = *(const bf16x8*)(Wup + (size_t)(((10 + kh) * 4 + c) * 64 + lane) * 8);
            bf16x8 b3 = *(const bf16x8*)(Wup + (size_t)(((18 + kh) * 4 + c) * 64 + lane) * 8);
            acc1[0][c] = __builtin_amdgcn_mfma_f32_16x16x32_bf16(a0, b1, acc1[0][c], 0, 0, 0);
            acc1[1][c] = __builtin_amdgcn_mfma_f32_16x16x32_bf16(a1, b1, acc1[1][c], 0, 0, 0);
            acc2[0][c] = __builtin_amdgcn_mfma_f32_16x16x32_bf16(a0, b2, acc2[0][c], 0, 0, 0);
            acc2[1][c] = __builtin_amdgcn_mfma_f32_16x16x32_bf16(a1, b2, acc2[1][c], 0, 0, 0);
            acc3[0][c] = __builtin_amdgcn_mfma_f32_16x16x32_bf16(a0, b3, acc3[0][c], 0, 0, 0);
            acc3[1][c] = __builtin_amdgcn_mfma_f32_16x16x32_bf16(a1, b3, acc3[1][c], 0, 0, 0);
        }
    }

    // epilogue: C/D frag layout col=lane&15, row=(lane>>4)*4+reg  [verified]
    float cs[4] = {}, css[4] = {};            // per-thread BN partials (4 cols)
    #pragma unroll
    for (int s = 0; s < 2; ++s) {
        int r0 = rb + s * 16 + kg * 4;
        float s1v[4], s2v[4];
        #pragma unroll
        for (int r = 0; r < 4; ++r) { s1v[r] = s1p[r0 + r]; s2v[r] = s2p[r0 + r]; }
        #pragma unroll
        for (int c = 0; c < 4; ++c) {
            int col = c * 16 + r16;
            float bval = bu[col];
            #pragma unroll
            for (int r = 0; r < 4; ++r) {
                int row = r0 + r;
                if (row < n) {
                    float v = (accx[s][c][r] + acc1[s][c][r]
                            + s1v[r] * acc2[s][c][r] + s2v[r] * acc3[s][c][r] + bval) * snorm;
                    z[(size_t)row * 64 + col] = v;
                    cs[c] += v;
                    css[c] = fmaf(v, v, css[c]);
                }
            }
        }
    }
    // butterfly over kg (lanes xor 16,32): all lanes end with the kg-sum
    #pragma unroll
    for (int c = 0; c < 4; ++c) {
        float a = cs[c];  a += __shfl_xor(a, 16); a += __shfl_xor(a, 32); cs[c] = a;
        float b = css[c]; b += __shfl_xor(b, 16); b += __shfl_xor(b, 32); css[c] = b;
    }
    if (lane < 16) {
        #pragma unroll
        for (int c = 0; c < 4; ++c) {
            bnl[w][0][c * 16 + lane] = cs[c];
            bnl[w][1][c * 16 + lane] = css[c];
        }
    }
    __syncthreads();
    if (t < 128) {
        int st = t >> 6, cc = t & 63;
        float tot = bnl[0][st][cc] + bnl[1][st][cc] + bnl[2][st][cc] + bnl[3][st][cc];
        atomicAdd(&bnacc[st * 64 + cc], tot);
    }
}

// ---------------- K8: BN normalize (in place on d_out, float4/thread) -------
__global__ __launch_bounds__(256) void bn_apply(
    float* __restrict__ z, const float* __restrict__ acc,
    const float* __restrict__ gamma, const float* __restrict__ beta, int n)
{
    float inv_n = 1.0f / (float)n;
    int tid = blockIdx.x * 256 + threadIdx.x;
    int c0 = (tid * 4) & 63;                    // fixed columns for this thread
    float sc[4], sh[4];
    #pragma unroll
    for (int k = 0; k < 4; ++k) {
        int c = c0 + k;
        float mu = acc[c] * inv_n;
        float var = acc[64 + c] * inv_n - mu * mu;
        if (var < 0.f) var = 0.f;
        float inv = rsqrtf(var + BN_EPS_C) * gamma[c];
        sc[k] = inv;
        sh[k] = beta[c] - mu * inv;
    }
    int total4 = n * 16;                        // n*64 / 4
    int stride = gridDim.x * 256;               // *4 floats: multiple of 64 ✓
    for (int i = tid; i < total4; i += stride) {
        float4 v = *(float4*)&z[(size_t)i * 4];
        v.x = fmaf(v.x, sc[0], sh[0]);
        v.y = fmaf(v.y, sc[1], sh[1]);
        v.z = fmaf(v.z, sc[2], sh[2]);
        v.w = fmaf(v.w, sc[3], sh[3]);
        *(float4*)&z[(size_t)i * 4] = v;
    }
}

extern "C" void kernel_launch(void* const* d_in, const int* in_sizes, int n_in,
                              void* d_out, int out_size, void* d_ws, size_t ws_size,
                              hipStream_t stream)
{
    const float* x     = (const float*)d_in[0];
    const float* Wm    = (const float*)d_in[1];
    const float* bm    = (const float*)d_in[2];
    const float* Wu    = (const float*)d_in[3];
    const float* bu    = (const float*)d_in[4];
    const float* gamma = (const float*)d_in[5];
    const float* beta  = (const float*)d_in[6];
    const int*   src   = (const int*)d_in[7];
    const int*   dst   = (const int*)d_in[8];

    int n = in_sizes[0] / 64;
    int e = in_sizes[7];
    int npad = ((n + 127) / 128) * 128;
    int nb = (n + 127) >> BSHIFT;          // buckets (<=512 for n<=65535)
    float* z = (float*)d_out;

    char* w = (char*)d_ws;
    size_t off = 0;
    auto take = [&](size_t bytes) -> void* {
        void* p = w + off;
        off = (off + bytes + 255) & ~(size_t)255;
        return p;
    };
    unsigned* Ab    = (unsigned*)take((size_t)npad * 32 * sizeof(unsigned));
    float*    B     = (float*)take((size_t)n * 64 * sizeof(float));
    unsigned* xbu   = (unsigned*)take((size_t)npad * 32 * sizeof(unsigned));
    unsigned* hbu   = (unsigned*)take((size_t)npad * 128 * sizeof(unsigned));
    float*    s1    = (float*)take((size_t)npad * sizeof(float));
    float*    s2    = (float*)take((size_t)npad * sizeof(float));
    short*    Wup   = (short*)take((size_t)26 * 4 * 64 * 8 * sizeof(short));
    int*      offs  = (int*)take((size_t)(n + 1) * sizeof(int));
    int*      csr   = (int*)take((size_t)e * sizeof(int));
    unsigned* prs   = (unsigned*)take((size_t)e * sizeof(unsigned));
    int*      bcnt  = (int*)take((size_t)NBMAX * sizeof(int));
    int*      gcur  = (int*)take((size_t)NBMAX * sizeof(int));
    float*    bnacc = (float*)take(128 * sizeof(float));

    (void)n_in; (void)out_size; (void)ws_size;

    int nb_chunk = (e + 4095) / 4096;

    proj_mfma<<<npad / 128, 256, 0, stream>>>(x, Wm, Ab, B, xbu, n,
                                              dst, bcnt, e, nb_chunk,
                                              Wu, Wup, gcur, bnacc);
    bin_scatter<<<nb_chunk, 256, 0, stream>>>(src, dst, bcnt, gcur, prs, e);
    csr_fill<<<nb, 128, 0, stream>>>(prs, bcnt, offs, csr, n, e);
    node_reduce<<<(npad + 3) / 4, 256, 0, stream>>>(Ab, B, bm, offs, csr, hbu, s1, s2, n, npad);

    float snorm = (float)(1.0 / sqrt((double)n));
    gemm_mfma<<<npad / 128, 256, 0, stream>>>((const short*)xbu, (const short*)hbu,
                                              s1, s2, Wup, bu, z, bnacc, n, snorm);

    bn_apply<<<512, 256, 0, stream>>>(z, bnacc, gamma, beta, n);
}